// Round 6
// baseline (68.992 us; speedup 1.0000x reference)
//
#include <hip/hip_runtime.h>
#include <hip/hip_fp16.h>

#define HW_PIX (1024*1024)
#define D_ATTR 16
#define V_VERTS 100000
#define F_FACES 200000

typedef float f4 __attribute__((ext_vector_type(4)));
typedef unsigned int u4 __attribute__((ext_vector_type(4)));

// ---------- pre-pass kernels (run every call; deterministic) ----------

// attributes f32 (V x 16) -> f16 table in ws. 4 floats per thread.
__global__ __launch_bounds__(256) void cvt_attr_kernel(
    const float* __restrict__ in, __half2* __restrict__ out) {
    int i = blockIdx.x * blockDim.x + threadIdx.x;
    const int n = V_VERTS * D_ATTR / 4;
    if (i >= n) return;
    f4 v = __builtin_nontemporal_load((const f4*)in + i);
    out[i*2 + 0] = __floats2half2_rn(v.x, v.y);
    out[i*2 + 1] = __floats2half2_rn(v.z, v.w);
}

// faces (F x 3 int32) -> packed 3x17-bit in uint64 (V < 2^17)
__global__ __launch_bounds__(256) void pack_faces_kernel(
    const int* __restrict__ faces, unsigned long long* __restrict__ pf) {
    int i = blockIdx.x * blockDim.x + threadIdx.x;
    if (i >= F_FACES) return;
    unsigned long long v0 = (unsigned)__builtin_nontemporal_load(faces + i*3 + 0);
    unsigned long long v1 = (unsigned)__builtin_nontemporal_load(faces + i*3 + 1);
    unsigned long long v2 = (unsigned)__builtin_nontemporal_load(faces + i*3 + 2);
    pf[i] = v0 | (v1 << 17) | (v2 << 34);
}

// ---------- main kernel (f16 gather path, nt streaming) ----------

// unpack one u32 (two packed f16) -> two f32
__device__ inline void cvt2(unsigned int w, float* f) {
    __half2 h = __builtin_bit_cast(__half2, w);
    float2 t = __half22float2(h);
    f[0] = t.x; f[1] = t.y;
}

__device__ inline void cvt8(u4 q, float* f) {
    cvt2(q.x, f + 0);
    cvt2(q.y, f + 2);
    cvt2(q.z, f + 4);
    cvt2(q.w, f + 6);
}

__global__ __launch_bounds__(256) void render_f16_kernel(
    const __half* __restrict__ attrH,               // V x 16 f16 (ws, L2-resident)
    const float* __restrict__ bary,                 // HW x 3 f32 (stream)
    const unsigned long long* __restrict__ pfaces,  // F packed (ws, L2-resident)
    const int* __restrict__ p2f,                    // HW int32 (stream)
    float* __restrict__ out,                        // HW x 16 f32 (stream)
    float* __restrict__ mask)                       // HW f32 (stream)
{
    int i = blockIdx.x * blockDim.x + threadIdx.x;
    if (i >= HW_PIX) return;

    int pf = __builtin_nontemporal_load(p2f + i);
    __builtin_nontemporal_store((pf != -1) ? 1.0f : 0.0f, mask + i);
    int f = (pf < 0) ? pf + F_FACES : pf;

    unsigned long long u = pfaces[f];          // cached (hot table)
    int v0 = (int)(u & 0x1FFFF);
    int v1 = (int)((u >> 17) & 0x1FFFF);
    int v2 = (int)((u >> 34) & 0x1FFFF);

    float b0 = __builtin_nontemporal_load(bary + i*3 + 0);
    float b1 = __builtin_nontemporal_load(bary + i*3 + 1);
    float b2 = __builtin_nontemporal_load(bary + i*3 + 2);

    const u4* A0 = (const u4*)(attrH + (size_t)v0 * D_ATTR);
    const u4* A1 = (const u4*)(attrH + (size_t)v1 * D_ATTR);
    const u4* A2 = (const u4*)(attrH + (size_t)v2 * D_ATTR);

    // issue all 6 gather loads up front (2 x 16B per 32B row); cached
    u4 r0a = A0[0], r0b = A0[1];
    u4 r1a = A1[0], r1b = A1[1];
    u4 r2a = A2[0], r2b = A2[1];

    float x0[16], x1[16], x2[16];
    cvt8(r0a, x0); cvt8(r0b, x0 + 8);
    cvt8(r1a, x1); cvt8(r1b, x1 + 8);
    cvt8(r2a, x2); cvt8(r2b, x2 + 8);

    float acc[16];
    #pragma unroll
    for (int q = 0; q < 16; ++q)
        acc[q] = b0*x0[q] + b1*x1[q] + b2*x2[q];

    f4* o = (f4*)(out + (size_t)i * D_ATTR);
    #pragma unroll
    for (int q = 0; q < 4; ++q) {
        f4 r = { acc[4*q], acc[4*q+1], acc[4*q+2], acc[4*q+3] };
        __builtin_nontemporal_store(r, o + q);
    }
}

// ---------- fallback (f32 gather, no ws) ----------

__global__ __launch_bounds__(256) void render_f32_kernel(
    const float* __restrict__ attributes,
    const float* __restrict__ bary,
    const int*   __restrict__ faces,
    const int*   __restrict__ p2f,
    float* __restrict__ out,
    float* __restrict__ mask)
{
    int i = blockIdx.x * blockDim.x + threadIdx.x;
    if (i >= HW_PIX) return;
    int pf = p2f[i];
    mask[i] = (pf != -1) ? 1.0f : 0.0f;
    int f = (pf < 0) ? pf + F_FACES : pf;
    int v0 = faces[f*3+0], v1 = faces[f*3+1], v2 = faces[f*3+2];
    float b0 = bary[i*3+0], b1 = bary[i*3+1], b2 = bary[i*3+2];
    const float4* a0 = (const float4*)(attributes + (size_t)v0 * D_ATTR);
    const float4* a1 = (const float4*)(attributes + (size_t)v1 * D_ATTR);
    const float4* a2 = (const float4*)(attributes + (size_t)v2 * D_ATTR);
    float4* o = (float4*)(out + (size_t)i * D_ATTR);
    #pragma unroll
    for (int q = 0; q < 4; ++q) {
        float4 p0 = a0[q], p1 = a1[q], p2 = a2[q], r;
        r.x = b0*p0.x + b1*p1.x + b2*p2.x;
        r.y = b0*p0.y + b1*p1.y + b2*p2.y;
        r.z = b0*p0.z + b1*p1.z + b2*p2.z;
        r.w = b0*p0.w + b1*p1.w + b2*p2.w;
        o[q] = r;
    }
}

extern "C" void kernel_launch(void* const* d_in, const int* in_sizes, int n_in,
                              void* d_out, int out_size, void* d_ws, size_t ws_size,
                              hipStream_t stream) {
    const float* attributes = (const float*)d_in[0];
    const float* bary       = (const float*)d_in[1];
    const int*   faces      = (const int*)d_in[2];
    const int*   p2f        = (const int*)d_in[3];

    float* out  = (float*)d_out;
    float* mask = (float*)d_out + (size_t)HW_PIX * D_ATTR;

    const size_t attrH_bytes = (size_t)V_VERTS * D_ATTR * 2;   // 3.2 MB
    const size_t pface_bytes = (size_t)F_FACES * 8;            // 1.6 MB
    dim3 block(256);

    if (ws_size >= attrH_bytes + pface_bytes) {
        __half* attrH = (__half*)d_ws;
        unsigned long long* pfaces =
            (unsigned long long*)((char*)d_ws + attrH_bytes);

        cvt_attr_kernel<<<(V_VERTS*D_ATTR/4 + 255)/256, block, 0, stream>>>(
            attributes, (__half2*)attrH);
        pack_faces_kernel<<<(F_FACES + 255)/256, block, 0, stream>>>(
            faces, pfaces);
        render_f16_kernel<<<(HW_PIX + 255)/256, block, 0, stream>>>(
            attrH, bary, pfaces, p2f, out, mask);
    } else {
        render_f32_kernel<<<(HW_PIX + 255)/256, block, 0, stream>>>(
            attributes, bary, faces, p2f, out, mask);
    }
}

// Round 7
// 55.918 us; speedup vs baseline: 1.2338x; 1.2338x over previous
//
#include <hip/hip_runtime.h>
#include <hip/hip_fp16.h>

#define HW_PIX (1024*1024)
#define D_ATTR 16
#define V_VERTS 100000
#define F_FACES 200000
#define LDS_STRIDE 20   // 16 floats + 4 pad: keeps 16B alignment, spreads banks

typedef float f4 __attribute__((ext_vector_type(4)));
typedef unsigned int u4 __attribute__((ext_vector_type(4)));

// ---------- pre-pass kernels (run every call; deterministic) ----------

// attributes f32 (V x 16) -> f16 table in ws. 4 floats per thread.
__global__ __launch_bounds__(256) void cvt_attr_kernel(
    const float* __restrict__ in, __half2* __restrict__ out) {
    int i = blockIdx.x * blockDim.x + threadIdx.x;
    const int n = V_VERTS * D_ATTR / 4;
    if (i >= n) return;
    f4 v = __builtin_nontemporal_load((const f4*)in + i);
    out[i*2 + 0] = __floats2half2_rn(v.x, v.y);
    out[i*2 + 1] = __floats2half2_rn(v.z, v.w);
}

// faces (F x 3 int32) -> packed 3x17-bit in uint64 (V < 2^17)
__global__ __launch_bounds__(256) void pack_faces_kernel(
    const int* __restrict__ faces, unsigned long long* __restrict__ pf) {
    int i = blockIdx.x * blockDim.x + threadIdx.x;
    if (i >= F_FACES) return;
    unsigned long long v0 = (unsigned)__builtin_nontemporal_load(faces + i*3 + 0);
    unsigned long long v1 = (unsigned)__builtin_nontemporal_load(faces + i*3 + 1);
    unsigned long long v2 = (unsigned)__builtin_nontemporal_load(faces + i*3 + 2);
    pf[i] = v0 | (v1 << 17) | (v2 << 34);
}

// ---------- main kernel (f16 gather, nt loads, LDS-transposed nt stores) ----------

__device__ inline void cvt2(unsigned int w, float* f) {
    __half2 h = __builtin_bit_cast(__half2, w);
    float2 t = __half22float2(h);
    f[0] = t.x; f[1] = t.y;
}

__device__ inline void cvt8(u4 q, float* f) {
    cvt2(q.x, f + 0);
    cvt2(q.y, f + 2);
    cvt2(q.z, f + 4);
    cvt2(q.w, f + 6);
}

__global__ __launch_bounds__(256) void render_f16_kernel(
    const __half* __restrict__ attrH,               // V x 16 f16 (ws, L2-resident)
    const float* __restrict__ bary,                 // HW x 3 f32 (nt stream)
    const unsigned long long* __restrict__ pfaces,  // F packed (ws, L2-resident)
    const int* __restrict__ p2f,                    // HW int32 (nt stream)
    float* __restrict__ out,                        // HW x 16 f32 (nt stream, full-line)
    float* __restrict__ mask)                       // HW f32 (nt stream, dense)
{
    __shared__ __align__(16) float lds[256 * LDS_STRIDE];

    int tid = threadIdx.x;
    int i = blockIdx.x * 256 + tid;

    int pf = __builtin_nontemporal_load(p2f + i);
    __builtin_nontemporal_store((pf != -1) ? 1.0f : 0.0f, mask + i);
    int f = (pf < 0) ? pf + F_FACES : pf;

    unsigned long long u = pfaces[f];          // cached (hot table)
    int v0 = (int)(u & 0x1FFFF);
    int v1 = (int)((u >> 17) & 0x1FFFF);
    int v2 = (int)((u >> 34) & 0x1FFFF);

    float b0 = __builtin_nontemporal_load(bary + i*3 + 0);
    float b1 = __builtin_nontemporal_load(bary + i*3 + 1);
    float b2 = __builtin_nontemporal_load(bary + i*3 + 2);

    const u4* A0 = (const u4*)(attrH + (size_t)v0 * D_ATTR);
    const u4* A1 = (const u4*)(attrH + (size_t)v1 * D_ATTR);
    const u4* A2 = (const u4*)(attrH + (size_t)v2 * D_ATTR);

    // issue all 6 gather loads up front (2 x 16B per 32B row); cached
    u4 r0a = A0[0], r0b = A0[1];
    u4 r1a = A1[0], r1b = A1[1];
    u4 r2a = A2[0], r2b = A2[1];

    float x0[16], x1[16], x2[16];
    cvt8(r0a, x0); cvt8(r0b, x0 + 8);
    cvt8(r1a, x1); cvt8(r1b, x1 + 8);
    cvt8(r2a, x2); cvt8(r2b, x2 + 8);

    // stage this pixel's 16 outputs in LDS (16B-aligned quads, stride 20)
    #pragma unroll
    for (int q = 0; q < 4; ++q) {
        f4 r = { b0*x0[4*q+0] + b1*x1[4*q+0] + b2*x2[4*q+0],
                 b0*x0[4*q+1] + b1*x1[4*q+1] + b2*x2[4*q+1],
                 b0*x0[4*q+2] + b1*x1[4*q+2] + b2*x2[4*q+2],
                 b0*x0[4*q+3] + b1*x1[4*q+3] + b2*x2[4*q+3] };
        *(f4*)&lds[tid * LDS_STRIDE + q * 4] = r;
    }

    __syncthreads();

    // transposed write-out: each wave store instruction covers 1KB contiguous
    f4* oblk = (f4*)(out + (size_t)blockIdx.x * (256 * D_ATTR));
    #pragma unroll
    for (int k = 0; k < 4; ++k) {
        int flat = k * 1024 + tid * 4;      // float index within block's 16KB
        int pix  = flat >> 4;               // local pixel
        int e    = flat & 15;               // element quad start
        f4 v = *(const f4*)&lds[pix * LDS_STRIDE + e];
        __builtin_nontemporal_store(v, oblk + k * 256 + tid);
    }
}

// ---------- fallback (f32 gather, no ws) ----------

__global__ __launch_bounds__(256) void render_f32_kernel(
    const float* __restrict__ attributes,
    const float* __restrict__ bary,
    const int*   __restrict__ faces,
    const int*   __restrict__ p2f,
    float* __restrict__ out,
    float* __restrict__ mask)
{
    int i = blockIdx.x * blockDim.x + threadIdx.x;
    if (i >= HW_PIX) return;
    int pf = p2f[i];
    mask[i] = (pf != -1) ? 1.0f : 0.0f;
    int f = (pf < 0) ? pf + F_FACES : pf;
    int v0 = faces[f*3+0], v1 = faces[f*3+1], v2 = faces[f*3+2];
    float b0 = bary[i*3+0], b1 = bary[i*3+1], b2 = bary[i*3+2];
    const float4* a0 = (const float4*)(attributes + (size_t)v0 * D_ATTR);
    const float4* a1 = (const float4*)(attributes + (size_t)v1 * D_ATTR);
    const float4* a2 = (const float4*)(attributes + (size_t)v2 * D_ATTR);
    float4* o = (float4*)(out + (size_t)i * D_ATTR);
    #pragma unroll
    for (int q = 0; q < 4; ++q) {
        float4 p0 = a0[q], p1 = a1[q], p2 = a2[q], r;
        r.x = b0*p0.x + b1*p1.x + b2*p2.x;
        r.y = b0*p0.y + b1*p1.y + b2*p2.y;
        r.z = b0*p0.z + b1*p1.z + b2*p2.z;
        r.w = b0*p0.w + b1*p1.w + b2*p2.w;
        o[q] = r;
    }
}

extern "C" void kernel_launch(void* const* d_in, const int* in_sizes, int n_in,
                              void* d_out, int out_size, void* d_ws, size_t ws_size,
                              hipStream_t stream) {
    const float* attributes = (const float*)d_in[0];
    const float* bary       = (const float*)d_in[1];
    const int*   faces      = (const int*)d_in[2];
    const int*   p2f        = (const int*)d_in[3];

    float* out  = (float*)d_out;
    float* mask = (float*)d_out + (size_t)HW_PIX * D_ATTR;

    const size_t attrH_bytes = (size_t)V_VERTS * D_ATTR * 2;   // 3.2 MB
    const size_t pface_bytes = (size_t)F_FACES * 8;            // 1.6 MB
    dim3 block(256);

    if (ws_size >= attrH_bytes + pface_bytes) {
        __half* attrH = (__half*)d_ws;
        unsigned long long* pfaces =
            (unsigned long long*)((char*)d_ws + attrH_bytes);

        cvt_attr_kernel<<<(V_VERTS*D_ATTR/4 + 255)/256, block, 0, stream>>>(
            attributes, (__half2*)attrH);
        pack_faces_kernel<<<(F_FACES + 255)/256, block, 0, stream>>>(
            faces, pfaces);
        render_f16_kernel<<<HW_PIX / 256, block, 0, stream>>>(
            attrH, bary, pfaces, p2f, out, mask);
    } else {
        render_f32_kernel<<<(HW_PIX + 255)/256, block, 0, stream>>>(
            attributes, bary, faces, p2f, out, mask);
    }
}